// Round 3
// baseline (435.963 us; speedup 1.0000x reference)
//
#include <hip/hip_runtime.h>

// RouteNet f32. Structure: stats -> prep -> bias/bfold -> k_gemm3(K-split-4, no atomics)
// -> k_act(reduce+bias+relu+bank0-stats) -> 15x k_bank (launch boundary = BN barrier) -> k_out.
// Round 7: k_out rewritten (123->~20us): 64x128 tile, acc[8][4], grid (128,8).
// Round 8: k_gemm3 double-buffered (1 sync/kc, reg prefetch); k_stats grid (12,64).
// Round 9 (this): fix R8 correctness bug -- k_act may only emit BANK-0 stats.
// Bank 1 gets edge-updated in k_bank t=1 which emits its stats; adding pre-edge
// bank-1 stats in k_act double-counted (absmax 62.5). Bank 0 has no edges ->
// its k_act value is final, stats valid, k_bank t=0 (pure stats pass) stays dropped.

#define BATCH 8192
#define NIN 3072
#define DD 32
#define NB 16
#define NOUT 1000
#define TGOFF (BATCH * NOUT)
#define BNEPS 1e-5f

// ws float offsets
#define O_SUM 0          // [3072]
#define O_SUM2 3072      // [3072]
#define O_STATS2 6144    // [16 banks][16 slots][64] sum/sumsq
#define O_TG 22528       // [8192]
#define ZERO_FLOATS 30720
#define O_SCALE 30720    // [3072]
#define O_SHIFT 33792    // [3072]
#define O_BIAS 36864     // [64]
#define O_BP 36928       // [3072][64] folded B'
#define O_ACTS 233536    // [16][8192][32] raw acts (f32)
// O_ACC reuses acts banks 2..9 (dead until k_bank t=2, which runs after k_act)
#define O_ACC (O_ACTS + 2 * BATCH * DD)   // [4][8192][64] gemm partials
// total ws = 233536 + 16*8192*32 = 4,427,840 floats (~16.9 MB)

// ---- K1: column stats of x ----
__global__ void __launch_bounds__(256) k_stats(const float* __restrict__ x, float* __restrict__ ws) {
    int c = blockIdx.x * 256 + threadIdx.x;                  // 12 x-blocks
    const float* p = x + (size_t)blockIdx.y * 128 * NIN + c; // 64 y-blocks x 128 rows
    float s = 0.f, s2 = 0.f;
#pragma unroll 8
    for (int i = 0; i < 128; i++) { float v = p[(size_t)i * NIN]; s += v; s2 += v * v; }
    atomicAdd(&ws[O_SUM + c], s);
    atomicAdd(&ws[O_SUM2 + c], s2);
}

// ---- K2: scale/shift; seed fused bias with b_in ----
__global__ void __launch_bounds__(256) k_prep(float* __restrict__ ws, const float* __restrict__ g,
                                              const float* __restrict__ b, const float* __restrict__ b_in) {
    int c = blockIdx.x * 256 + threadIdx.x;
    float mean = ws[O_SUM + c] * (1.f / BATCH);
    float var = ws[O_SUM2 + c] * (1.f / BATCH) - mean * mean;
    float sc = g[c] * rsqrtf(fmaxf(var, 0.f) + BNEPS);
    ws[O_SCALE + c] = sc;
    ws[O_SHIFT + c] = b[c] - mean * sc;
    if (c < 64) ws[O_BIAS + c] = b_in[c];
}

// ---- K3a: bias' += shift @ W_in ----
__global__ void __launch_bounds__(256) k_bias(float* __restrict__ ws, const float* __restrict__ W_in) {
    int bank = blockIdx.x & 1, jc = blockIdx.x >> 1;
    int d = threadIdx.x & 31, js = threadIdx.x >> 5;
    int j0 = jc * 256 + js * 32;
    float a = 0.f;
    for (int j = 0; j < 32; j++)
        a += ws[O_SHIFT + j0 + j] * W_in[(size_t)bank * NIN * DD + (size_t)(j0 + j) * DD + d];
    __shared__ float red[8][32];
    red[js][d] = a;
    __syncthreads();
    if (threadIdx.x < 32) {
        float t = 0.f;
#pragma unroll
        for (int g8 = 0; g8 < 8; g8++) t += red[g8][threadIdx.x];
        atomicAdd(&ws[O_BIAS + bank * 32 + threadIdx.x], t);
    }
}

// ---- K3b: B'[j][c] = scale[j] * W_in[c>>5][j][c&31] ----
__global__ void __launch_bounds__(256) k_bfold(float* __restrict__ ws, const float* __restrict__ W_in) {
    int idx = blockIdx.x * 256 + threadIdx.x;
    int j = idx >> 6, c = idx & 63;
    ws[O_BP + idx] = ws[O_SCALE + j] * W_in[(size_t)(c >> 5) * NIN * DD + (size_t)j * DD + (c & 31)];
}

// ---- K4: input GEMM. grid (128,4): 64 rows x 64 cols per block, K-split 4 (768 each).
// Double-buffered LDS: reg-prefetch tile kc+1 at loop top (hides ~500cy global latency
// under 256 FMA insts), single __syncthreads per kc. ----
__global__ void __launch_bounds__(256) k_gemm3(const float* __restrict__ x, float* __restrict__ ws) {
    __shared__ float xL[2][64][20];   // 16 k + pad4
    __shared__ float bL[2][16][64];
    int tid = threadIdx.x;
    int row0 = blockIdx.x * 64;
    int k00 = blockIdx.y * 768;
    const float* bp = ws + O_BP;
    float acc[4][4] = {};
    int tx = tid & 15, rt = tid >> 4;      // cols tx*4, rows rt*4
    int lr = tid >> 2, lq = tid & 3;       // x loader
    int br = tid >> 4, bq = tid & 15;      // b loader
    const float* xp = &x[(size_t)(row0 + lr) * NIN + k00 + lq * 4];
    const float* bpp = &bp[(size_t)(k00 + br) * 64 + bq * 4];
    // preload tile 0
    float4 xv = *(const float4*)xp;
    float4 bv = *(const float4*)bpp;
    *(float4*)&xL[0][lr][lq * 4] = xv;
    *(float4*)&bL[0][br][bq * 4] = bv;
    __syncthreads();
#pragma unroll 2
    for (int kc = 0; kc < 48; kc++) {
        int cur = kc & 1;
        if (kc < 47) {
            xv = *(const float4*)(xp + (kc + 1) * 16);
            bv = *(const float4*)(bpp + (size_t)(kc + 1) * 1024);
        }
#pragma unroll
        for (int kk = 0; kk < 16; kk += 4) {
            float4 b0 = *(float4*)&bL[cur][kk][tx * 4];
            float4 b1 = *(float4*)&bL[cur][kk + 1][tx * 4];
            float4 b2 = *(float4*)&bL[cur][kk + 2][tx * 4];
            float4 b3 = *(float4*)&bL[cur][kk + 3][tx * 4];
#pragma unroll
            for (int j = 0; j < 4; j++) {
                float4 xv4 = *(float4*)&xL[cur][rt * 4 + j][kk];
                acc[j][0] += xv4.x * b0.x + xv4.y * b1.x + xv4.z * b2.x + xv4.w * b3.x;
                acc[j][1] += xv4.x * b0.y + xv4.y * b1.y + xv4.z * b2.y + xv4.w * b3.y;
                acc[j][2] += xv4.x * b0.z + xv4.y * b1.z + xv4.z * b2.z + xv4.w * b3.z;
                acc[j][3] += xv4.x * b0.w + xv4.y * b1.w + xv4.z * b2.w + xv4.w * b3.w;
            }
        }
        if (kc < 47) {
            *(float4*)&xL[cur ^ 1][lr][lq * 4] = xv;
            *(float4*)&bL[cur ^ 1][br][bq * 4] = bv;
        }
        __syncthreads();
    }
    float* dst = ws + O_ACC + (size_t)blockIdx.y * (BATCH * 64);
#pragma unroll
    for (int j = 0; j < 4; j++) {
        float4 v = make_float4(acc[j][0], acc[j][1], acc[j][2], acc[j][3]);
        *(float4*)&dst[(size_t)(row0 + rt * 4 + j) * 64 + tx * 4] = v;
    }
}

// ---- K5: reduce 4 K-split partials + bias + relu -> acts banks 0/1; emit BANK-0
// BN stats only (bank 0 has no incoming edges -> value is final here; bank 1 is
// edge-updated in k_bank t=1 which emits its stats). Block = 16 rows x 64 cols.
__global__ void __launch_bounds__(256) k_act(float* __restrict__ ws) {
    __shared__ float sred[16][32];
    __shared__ float qred[16][32];
    int tid = threadIdx.x;
    int i4 = (blockIdx.x * 256 + tid) * 4;  // 512 blocks cover 8192*64
    const float* ac = ws + O_ACC;
    float4 s0 = *(const float4*)&ac[i4];
    float4 s1 = *(const float4*)&ac[524288 + i4];
    float4 s2 = *(const float4*)&ac[1048576 + i4];
    float4 s3 = *(const float4*)&ac[1572864 + i4];
    int c = i4 & 63, row = i4 >> 6;
    const float* bias = ws + O_BIAS;
    float4 v;
    v.x = fmaxf(s0.x + s1.x + s2.x + s3.x + bias[c], 0.f);
    v.y = fmaxf(s0.y + s1.y + s2.y + s3.y + bias[c + 1], 0.f);
    v.z = fmaxf(s0.z + s1.z + s2.z + s3.z + bias[c + 2], 0.f);
    v.w = fmaxf(s0.w + s1.w + s2.w + s3.w + bias[c + 3], 0.f);
    int bank = c >> 5, dd = c & 31;
    *(float4*)&ws[O_ACTS + ((size_t)bank * BATCH + row) * DD + dd] = v;
    // bank-0 stats only: cols 0..31 (bank==0 <=> c<32)
    int r16 = tid >> 4;           // row within block
    if (bank == 0) {
        *(float4*)&sred[r16][dd] = v;
        *(float4*)&qred[r16][dd] = make_float4(v.x * v.x, v.y * v.y, v.z * v.z, v.w * v.w);
    }
    __syncthreads();
    if (tid < 32) {
        float sm = 0.f, sq = 0.f;
#pragma unroll
        for (int r = 0; r < 16; r++) { sm += sred[r][tid]; sq += qred[r][tid]; }
        int slot = blockIdx.x & 15;
        float* st = ws + O_STATS2 + (size_t)slot * 64;   // bank 0
        atomicAdd(&st[tid], sm);
        atomicAdd(&st[32 + tid], sq);
    }
}

// ---- K6 (x15, t=1..15): one bank. 1024 blocks x 8 rows; Wd prefetched; scalar accumulator. ----
__global__ void __launch_bounds__(256) k_bank(int t, float* __restrict__ ws,
                                              const float* __restrict__ Wg, const float* __restrict__ Wd,
                                              const float* __restrict__ bd) {
    __shared__ float asrcL[4][8][32];
    __shared__ float WdL[4][1024];
    __shared__ float mML[4][32], ivL[4][32];
    __shared__ float red[8][64];
    int tid = threadIdx.x;
    int rg = tid >> 5, d = tid & 31;
    int row0 = blockIdx.x * 8;
    int slot = blockIdx.x & 15;
    float* acts = ws + O_ACTS;
    float* stats = ws + O_STATS2;
    int nE = t < 4 ? t : 4;
    int s0 = t - nE;
    int eb = (t <= 4) ? t * (t - 1) / 2 : 10 + 4 * (t - 5);
    // prefetch all edge Wd (contiguous) into LDS
    for (int p = tid; p < nE * 256; p += 256)
        ((float4*)&WdL[0][0])[p] = ((const float4*)(Wd + (size_t)eb * 1024))[p];
    // per-edge Wg/bd rows into registers (const-indexed)
    float wgr[4], bdr[4];
#pragma unroll
    for (int ei = 0; ei < 4; ei++) {
        wgr[ei] = (ei < nE) ? Wg[(eb + ei) * 32 + d] : 0.f;
        bdr[ei] = (ei < nE) ? bd[(eb + ei) * 32 + d] : 0.f;
    }
    // source-bank BN params
    if (tid < nE * 32) {
        int si = tid >> 5, dd = tid & 31;
        const float* st = stats + (size_t)(s0 + si) * 16 * 64;
        float sm = 0.f, sq = 0.f;
#pragma unroll
        for (int sl = 0; sl < 16; sl++) { sm += st[sl * 64 + dd]; sq += st[sl * 64 + 32 + dd]; }
        float m = sm * (1.f / BATCH);
        float var = sq * (1.f / BATCH) - m * m;
        mML[si][dd] = m;
        ivL[si][dd] = rsqrtf(fmaxf(var, 0.f) + BNEPS);
    }
    float cur = (t < 2) ? acts[((size_t)t * BATCH + row0 + rg) * DD + d] : 0.f;
    __syncthreads();
#pragma unroll 4
    for (int si = 0; si < nE; si++)
        asrcL[si][rg][d] = (acts[((size_t)(s0 + si) * BATCH + row0 + rg) * DD + d] - mML[si][d]) * ivL[si][d];
    __syncthreads();
    float tg = 0.f;
#pragma unroll
    for (int ei = 0; ei < 4; ei++) {
        if (ei < nE) {
            float g = asrcL[ei][rg][d] * wgr[ei];
            g += __shfl_xor(g, 1); g += __shfl_xor(g, 2); g += __shfl_xor(g, 4);
            g += __shfl_xor(g, 8); g += __shfl_xor(g, 16);
            g = fminf(fmaxf(g, 0.f), 1.f);
            tg += g;
            float dat = bdr[ei];
            const float* ar = asrcL[ei][rg];
            const float* wc = &WdL[ei][d];
#pragma unroll
            for (int k = 0; k < 32; k += 4) {
                float4 a4 = *(const float4*)&ar[k];
                dat += a4.x * wc[k * 32] + a4.y * wc[(k + 1) * 32]
                     + a4.z * wc[(k + 2) * 32] + a4.w * wc[(k + 3) * 32];
            }
            cur += g * dat;
        }
    }
    float v = fmaxf(cur, 0.f);
    acts[((size_t)t * BATCH + row0 + rg) * DD + d] = v;
    if (d == 0 && nE > 0) ws[O_TG + row0 + rg] += tg;
    red[rg][d] = v; red[rg][32 + d] = v * v;
    __syncthreads();
    if (tid < 64) {
        float a = 0.f;
#pragma unroll
        for (int g8 = 0; g8 < 8; g8++) a += red[g8][tid];
        atomicAdd(&stats[((size_t)t * 16 + slot) * 64 + tid], a);
    }
}

// ---- K7: output GEMM [8192x64]@[64x1000] -> f32 out; copy total_gate ----
// 64 rows x 128 cols per block, grid (128,8). acc[8][4] per thread.
__global__ void __launch_bounds__(256) k_out(const float* __restrict__ ws, const float* __restrict__ Wout,
                                             float* __restrict__ out) {
    __shared__ float aLt[32][68];    // [d][row], pad to 68 (16B-aligned rows)
    __shared__ float wL[32][128];    // [k][col]
    __shared__ float mIv[2][2][32];  // [bank][m|iv][d]
    int tid = threadIdx.x;
    int row0 = blockIdx.x * 64;
    int col0 = blockIdx.y * 128;
    const float* acts = ws + O_ACTS;
    // total_gate copy (one col-block only): 128 row-blocks x 64 = 8192
    if (blockIdx.y == 0 && tid < 64) out[TGOFF + row0 + tid] = ws[O_TG + row0 + tid];
    // BN stats for banks 14,15
    if (tid < 64) {
        int bi = tid >> 5, d = tid & 31;
        const float* st = ws + O_STATS2 + (size_t)(14 + bi) * 16 * 64;
        float sm = 0.f, sq = 0.f;
#pragma unroll
        for (int sl = 0; sl < 16; sl++) { sm += st[sl * 64 + d]; sq += st[sl * 64 + 32 + d]; }
        float m = sm * (1.f / BATCH);
        float var = sq * (1.f / BATCH) - m * m;
        mIv[bi][0][d] = m;
        mIv[bi][1][d] = rsqrtf(fmaxf(var, 0.f) + BNEPS);
    }
    int tx = tid & 31, ty = tid >> 5;   // tx: 4-col group, ty: 8-row group
    int c4 = col0 + tx * 4;
    bool c4ok = (c4 + 3 < NOUT);
    float acc[8][4] = {};
    for (int bi = 0; bi < 2; bi++) {
        __syncthreads();  // first iter: mIv ready; later: protect LDS reuse
        // stage acts bank 14+bi transposed + BN: aLt[d][r]
        {
            int d = tid & 31, r0 = tid >> 5;
            float m = mIv[bi][0][d], iv = mIv[bi][1][d];
            const float* ap = acts + ((size_t)(14 + bi) * BATCH + row0) * DD + d;
#pragma unroll
            for (int i = 0; i < 8; i++) {
                int r = r0 + 8 * i;
                aLt[d][r] = (ap[(size_t)r * DD] - m) * iv;
            }
        }
        // stage Wout[bi] tile [32 k][128 cols]
        {
            const float* wp = Wout + (size_t)bi * DD * NOUT + c4;
            int kk0 = tid >> 5;
#pragma unroll
            for (int i = 0; i < 4; i++) {
                int kk = kk0 + 8 * i;
                const float* wr = wp + (size_t)kk * NOUT;
                float4 v;
                if (c4ok) {
                    v = *(const float4*)wr;
                } else {
                    v.x = (c4 + 0 < NOUT) ? wr[0] : 0.f;
                    v.y = (c4 + 1 < NOUT) ? wr[1] : 0.f;
                    v.z = (c4 + 2 < NOUT) ? wr[2] : 0.f;
                    v.w = (c4 + 3 < NOUT) ? wr[3] : 0.f;
                }
                *(float4*)&wL[kk][tx * 4] = v;
            }
        }
        __syncthreads();
#pragma unroll 4
        for (int k = 0; k < 32; k++) {
            float4 w = *(float4*)&wL[k][tx * 4];
            float4 a0 = *(float4*)&aLt[k][ty * 8];
            float4 a1 = *(float4*)&aLt[k][ty * 8 + 4];
            float ar[8] = {a0.x, a0.y, a0.z, a0.w, a1.x, a1.y, a1.z, a1.w};
            float wc[4] = {w.x, w.y, w.z, w.w};
#pragma unroll
            for (int r = 0; r < 8; r++)
#pragma unroll
                for (int c = 0; c < 4; c++)
                    acc[r][c] += ar[r] * wc[c];
        }
    }
    if (c4ok) {
#pragma unroll
        for (int r = 0; r < 8; r++) {
            int row = row0 + ty * 8 + r;
            *(float4*)&out[(size_t)row * NOUT + c4] =
                make_float4(acc[r][0], acc[r][1], acc[r][2], acc[r][3]);
        }
    } else {
#pragma unroll
        for (int r = 0; r < 8; r++) {
            int row = row0 + ty * 8 + r;
#pragma unroll
            for (int c = 0; c < 4; c++)
                if (c4 + c < NOUT) out[(size_t)row * NOUT + c4 + c] = acc[r][c];
        }
    }
}

extern "C" void kernel_launch(void* const* d_in, const int* in_sizes, int n_in,
                              void* d_out, int out_size, void* d_ws, size_t ws_size,
                              hipStream_t stream) {
    (void)in_sizes; (void)n_in; (void)out_size; (void)ws_size;
    const float* x     = (const float*)d_in[0];
    const float* gamma = (const float*)d_in[1];
    const float* beta  = (const float*)d_in[2];
    const float* W_in  = (const float*)d_in[3];
    const float* b_in  = (const float*)d_in[4];
    const float* Wg    = (const float*)d_in[5];
    const float* Wd    = (const float*)d_in[6];
    const float* bd    = (const float*)d_in[7];
    const float* Wout  = (const float*)d_in[8];
    float* out = (float*)d_out;
    float* ws  = (float*)d_ws;

    hipMemsetAsync(d_ws, 0, ZERO_FLOATS * sizeof(float), stream);
    k_stats<<<dim3(12, 64), 256, 0, stream>>>(x, ws);
    k_prep<<<12, 256, 0, stream>>>(ws, gamma, beta, b_in);
    k_bias<<<24, 256, 0, stream>>>(ws, W_in);
    k_bfold<<<768, 256, 0, stream>>>(ws, W_in);
    k_gemm3<<<dim3(128, 4), 256, 0, stream>>>(x, ws);
    k_act<<<512, 256, 0, stream>>>(ws);
    for (int t = 1; t < NB; t++)
        k_bank<<<1024, 256, 0, stream>>>(t, ws, Wg, Wd, bd);
    k_out<<<dim3(128, 8), 256, 0, stream>>>(ws, Wout, out);
}

// Round 4
// 432.968 us; speedup vs baseline: 1.0069x; 1.0069x over previous
//
#include <hip/hip_runtime.h>

// RouteNet f32. Structure: stats -> prep -> bias/bfold -> k_gemm3 -> k_act(+bank0 stats)
// -> k_banks (FUSED persistent kernel, 15 stages, atomic-flag barriers) -> k_out.
// Round 7: k_out rewritten (123->~20us): 64x128 tile, acc[8][4], grid (128,8).
// Round 8/9 lesson: k_gemm3 double-buffer regressed (VGPR 56->152, occ 18.8->10.6%,
//   97us) -> REVERTED to single-buffer R0 version (71.6us).
// Round 10 (this): 15x k_bank launches (~19us each, ~280us total; launch boundary only
// for BN-stats visibility) fused into ONE kernel. Each block owns 16 rows for ALL banks;
// raw acts kept in a 4-deep LDS ring (BAND=4); only cross-block data = 64-float stats
// per bank, exchanged via device-scope atomicAdd + flag barrier (spin on agent-scope
// atomic load; no L2 writeback needed since all inter-block traffic is atomics).
// 512 blocks = exactly 2/CU (LDS ~52KB<=80KB, launch_bounds(256,2)) -> co-residency
// guaranteed by capacity; deadlock risk accepted with 2x margins.

#define BATCH 8192
#define NIN 3072
#define DD 32
#define NB 16
#define NOUT 1000
#define TGOFF (BATCH * NOUT)
#define BNEPS 1e-5f
#define NBLK 512
#define ROWS 16

// ws float offsets
#define O_SUM 0          // [3072] (dead after k_prep; first 16 reused as barrier flags)
#define O_FLAG 0         // [16] int flags, re-zeroed by memset after k_prep
#define O_SUM2 3072      // [3072]
#define O_STATS2 6144    // [16 banks][16 slots][64] sum/sumsq
#define O_TG 22528       // [8192]
#define ZERO_FLOATS 30720
#define O_SCALE 30720    // [3072]
#define O_SHIFT 33792    // [3072]
#define O_BIAS 36864     // [64]
#define O_BP 36928       // [3072][64] folded B'
#define O_ACTS 233536    // [16][8192][32] raw acts (f32; only banks 0,1,14,15 used now)
#define O_ACC (O_ACTS + 2 * BATCH * DD)   // [4][8192][64] gemm partials (banks 2..9 reuse)

// ---- K1: column stats of x ----
__global__ void __launch_bounds__(256) k_stats(const float* __restrict__ x, float* __restrict__ ws) {
    int c = blockIdx.x * 256 + threadIdx.x;                  // 12 x-blocks
    const float* p = x + (size_t)blockIdx.y * 128 * NIN + c; // 64 y-blocks x 128 rows
    float s = 0.f, s2 = 0.f;
#pragma unroll 8
    for (int i = 0; i < 128; i++) { float v = p[(size_t)i * NIN]; s += v; s2 += v * v; }
    atomicAdd(&ws[O_SUM + c], s);
    atomicAdd(&ws[O_SUM2 + c], s2);
}

// ---- K2: scale/shift; seed fused bias with b_in ----
__global__ void __launch_bounds__(256) k_prep(float* __restrict__ ws, const float* __restrict__ g,
                                              const float* __restrict__ b, const float* __restrict__ b_in) {
    int c = blockIdx.x * 256 + threadIdx.x;
    float mean = ws[O_SUM + c] * (1.f / BATCH);
    float var = ws[O_SUM2 + c] * (1.f / BATCH) - mean * mean;
    float sc = g[c] * rsqrtf(fmaxf(var, 0.f) + BNEPS);
    ws[O_SCALE + c] = sc;
    ws[O_SHIFT + c] = b[c] - mean * sc;
    if (c < 64) ws[O_BIAS + c] = b_in[c];
}

// ---- K3a: bias' += shift @ W_in ----
__global__ void __launch_bounds__(256) k_bias(float* __restrict__ ws, const float* __restrict__ W_in) {
    int bank = blockIdx.x & 1, jc = blockIdx.x >> 1;
    int d = threadIdx.x & 31, js = threadIdx.x >> 5;
    int j0 = jc * 256 + js * 32;
    float a = 0.f;
    for (int j = 0; j < 32; j++)
        a += ws[O_SHIFT + j0 + j] * W_in[(size_t)bank * NIN * DD + (size_t)(j0 + j) * DD + d];
    __shared__ float red[8][32];
    red[js][d] = a;
    __syncthreads();
    if (threadIdx.x < 32) {
        float t = 0.f;
#pragma unroll
        for (int g8 = 0; g8 < 8; g8++) t += red[g8][threadIdx.x];
        atomicAdd(&ws[O_BIAS + bank * 32 + threadIdx.x], t);
    }
}

// ---- K3b: B'[j][c] = scale[j] * W_in[c>>5][j][c&31] ----
__global__ void __launch_bounds__(256) k_bfold(float* __restrict__ ws, const float* __restrict__ W_in) {
    int idx = blockIdx.x * 256 + threadIdx.x;
    int j = idx >> 6, c = idx & 63;
    ws[O_BP + idx] = ws[O_SCALE + j] * W_in[(size_t)(c >> 5) * NIN * DD + (size_t)j * DD + (c & 31)];
}

// ---- K4: input GEMM. grid (128,4): 64 rows x 64 cols per block, K-split 4 (768 each).
// R0 proven version (71.6us, VGPR 56) -- double-buffer variant regressed, do not re-add.
__global__ void __launch_bounds__(256) k_gemm3(const float* __restrict__ x, float* __restrict__ ws) {
    __shared__ float xL[64][20];   // 16 k + pad4
    __shared__ float bL[16][64];
    int tid = threadIdx.x;
    int row0 = blockIdx.x * 64;
    int k00 = blockIdx.y * 768;
    const float* bp = ws + O_BP;
    float acc[4][4] = {};
    int tx = tid & 15, rt = tid >> 4;      // cols tx*4, rows rt*4
    int lr = tid >> 2, lq = tid & 3;       // x loader
    int br = tid >> 4, bq = tid & 15;      // b loader
    for (int kc = 0; kc < 48; kc++) {
        int k0 = k00 + kc * 16;
        float4 xv = *(const float4*)&x[(size_t)(row0 + lr) * NIN + k0 + lq * 4];
        float4 bv = *(const float4*)&bp[(size_t)(k0 + br) * 64 + bq * 4];
        __syncthreads();
        *(float4*)&xL[lr][lq * 4] = xv;
        *(float4*)&bL[br][bq * 4] = bv;
        __syncthreads();
#pragma unroll
        for (int kk = 0; kk < 16; kk += 4) {
            float4 b0 = *(float4*)&bL[kk][tx * 4];
            float4 b1 = *(float4*)&bL[kk + 1][tx * 4];
            float4 b2 = *(float4*)&bL[kk + 2][tx * 4];
            float4 b3 = *(float4*)&bL[kk + 3][tx * 4];
#pragma unroll
            for (int j = 0; j < 4; j++) {
                float4 xv4 = *(float4*)&xL[rt * 4 + j][kk];
                acc[j][0] += xv4.x * b0.x + xv4.y * b1.x + xv4.z * b2.x + xv4.w * b3.x;
                acc[j][1] += xv4.x * b0.y + xv4.y * b1.y + xv4.z * b2.y + xv4.w * b3.y;
                acc[j][2] += xv4.x * b0.z + xv4.y * b1.z + xv4.z * b2.z + xv4.w * b3.z;
                acc[j][3] += xv4.x * b0.w + xv4.y * b1.w + xv4.z * b2.w + xv4.w * b3.w;
            }
        }
    }
    float* dst = ws + O_ACC + (size_t)blockIdx.y * (BATCH * 64);
#pragma unroll
    for (int j = 0; j < 4; j++) {
        float4 v = make_float4(acc[j][0], acc[j][1], acc[j][2], acc[j][3]);
        *(float4*)&dst[(size_t)(row0 + rt * 4 + j) * 64 + tx * 4] = v;
    }
}

// ---- K5: reduce 4 K-split partials + bias + relu -> acts banks 0/1; emit BANK-0
// BN stats only (bank 0 value is final here; bank 1 is edge-updated in stage 1).
__global__ void __launch_bounds__(256) k_act(float* __restrict__ ws) {
    __shared__ float sred[16][32];
    __shared__ float qred[16][32];
    int tid = threadIdx.x;
    int i4 = (blockIdx.x * 256 + tid) * 4;  // 512 blocks cover 8192*64
    const float* ac = ws + O_ACC;
    float4 s0 = *(const float4*)&ac[i4];
    float4 s1 = *(const float4*)&ac[524288 + i4];
    float4 s2 = *(const float4*)&ac[1048576 + i4];
    float4 s3 = *(const float4*)&ac[1572864 + i4];
    int c = i4 & 63, row = i4 >> 6;
    const float* bias = ws + O_BIAS;
    float4 v;
    v.x = fmaxf(s0.x + s1.x + s2.x + s3.x + bias[c], 0.f);
    v.y = fmaxf(s0.y + s1.y + s2.y + s3.y + bias[c + 1], 0.f);
    v.z = fmaxf(s0.z + s1.z + s2.z + s3.z + bias[c + 2], 0.f);
    v.w = fmaxf(s0.w + s1.w + s2.w + s3.w + bias[c + 3], 0.f);
    int bank = c >> 5, dd = c & 31;
    *(float4*)&ws[O_ACTS + ((size_t)bank * BATCH + row) * DD + dd] = v;
    int r16 = tid >> 4;
    if (bank == 0) {
        *(float4*)&sred[r16][dd] = v;
        *(float4*)&qred[r16][dd] = make_float4(v.x * v.x, v.y * v.y, v.z * v.z, v.w * v.w);
    }
    __syncthreads();
    if (tid < 32) {
        float sm = 0.f, sq = 0.f;
#pragma unroll
        for (int r = 0; r < 16; r++) { sm += sred[r][tid]; sq += qred[r][tid]; }
        int slot = blockIdx.x & 15;
        float* st = ws + O_STATS2 + (size_t)slot * 64;   // bank 0
        atomicAdd(&st[tid], sm);
        atomicAdd(&st[32 + tid], sq);
    }
}

// ---- K6: ALL banks t=1..15 in one persistent kernel. 512 blocks x 16 rows (2/CU).
// LDS ring of raw acts (4 banks), m/iv ring, double-buffered Wd. Cross-block data =
// stats only (atomicAdd), barrier = flag atomicAdd + agent-scope spin.
__global__ void __launch_bounds__(256, 2) k_banks(float* __restrict__ ws,
                                                  const float* __restrict__ Wg,
                                                  const float* __restrict__ Wd,
                                                  const float* __restrict__ bd) {
    __shared__ float ring[4][ROWS][32];    // raw acts, bank s in slot s&3
    __shared__ float asrcL[4][ROWS][32];   // normalized sources for current stage
    __shared__ float WdL[2][4][1024];      // double-buffered edge weights
    __shared__ float mL[4][32], ivL[4][32];
    __shared__ float red[8][64];
    int tid = threadIdx.x;
    int rg = tid >> 5, d = tid & 31;
    int row0 = blockIdx.x * ROWS;
    int slot = blockIdx.x & 15;
    float* acts = ws + O_ACTS;
    float* stats = ws + O_STATS2;
    int* flag = (int*)(ws + O_FLAG);
    float tg[2] = {0.f, 0.f};
    float cur[2];
    // prologue: stash raw bank0 in ring slot 0; load bank1 partial (cur); bank0 m/iv
#pragma unroll
    for (int ri = 0; ri < 2; ri++) {
        int r = rg + 8 * ri;
        ring[0][r][d] = acts[(size_t)(row0 + r) * DD + d];
        cur[ri] = acts[((size_t)BATCH + row0 + r) * DD + d];
    }
    if (tid < 32) {
        const float* st = stats;  // bank 0 (k_act atomics, prior kernel)
        float sm = 0.f, sq = 0.f;
#pragma unroll
        for (int sl = 0; sl < 16; sl++) { sm += st[sl * 64 + tid]; sq += st[sl * 64 + 32 + tid]; }
        float m = sm * (1.f / BATCH);
        float var = sq * (1.f / BATCH) - m * m;
        mL[0][tid] = m;
        ivL[0][tid] = rsqrtf(fmaxf(var, 0.f) + BNEPS);
    }
    // prefetch Wd for stage 1 (edge 0 only) into WdL[1]
    if (tid < 256) {
        ((float4*)&WdL[1][0][0])[tid] = ((const float4*)Wd)[tid];
    }
    for (int t = 1; t < 16; t++) {
        int buf = t & 1;
        int nE = t < 4 ? t : 4;
        int s0 = t - nE;
        int eb = (t <= 4) ? t * (t - 1) / 2 : 10 + 4 * (t - 5);
        // prefetch next stage's Wd into the other buffer (completes before next gemm)
        if (t < 15) {
            int t2 = t + 1;
            int nE2 = t2 < 4 ? t2 : 4;
            int eb2 = (t2 <= 4) ? t2 * (t2 - 1) / 2 : 10 + 4 * (t2 - 5);
            for (int p = tid; p < nE2 * 256; p += 256)
                ((float4*)&WdL[buf ^ 1][0][0])[p] = ((const float4*)(Wd + (size_t)eb2 * 1024))[p];
        }
        // per-stage Wg/bd rows (cached global)
        float wgr[4], bdr[4];
#pragma unroll
        for (int ei = 0; ei < 4; ei++) {
            wgr[ei] = (ei < nE) ? Wg[(eb + ei) * 32 + d] : 0.f;
            bdr[ei] = (ei < nE) ? bd[(eb + ei) * 32 + d] : 0.f;
        }
        if (t > 1) {
            // wait for all blocks' bank t-1 stats
            if (tid == 0) {
                while (__hip_atomic_load(&flag[t - 1], __ATOMIC_RELAXED, __HIP_MEMORY_SCOPE_AGENT) < NBLK)
                    __builtin_amdgcn_s_sleep(2);
            }
            __syncthreads();
            if (tid < 32) {
                const float* st = stats + (size_t)(t - 1) * 16 * 64;
                float sm = 0.f, sq = 0.f;
#pragma unroll
                for (int sl = 0; sl < 16; sl++) {
                    sm += __hip_atomic_load(&st[sl * 64 + tid], __ATOMIC_RELAXED, __HIP_MEMORY_SCOPE_AGENT);
                    sq += __hip_atomic_load(&st[sl * 64 + 32 + tid], __ATOMIC_RELAXED, __HIP_MEMORY_SCOPE_AGENT);
                }
                float m = sm * (1.f / BATCH);
                float var = sq * (1.f / BATCH) - m * m;
                mL[(t - 1) & 3][tid] = m;
                ivL[(t - 1) & 3][tid] = rsqrtf(fmaxf(var, 0.f) + BNEPS);
            }
        }
        __syncthreads();   // m/iv ready; prior-stage asrcL reads done (post-gemm sync)
        // build normalized source tiles from raw ring
#pragma unroll
        for (int si = 0; si < 4; si++) {
            if (si < nE) {
                int sl4 = (s0 + si) & 3;
#pragma unroll
                for (int ri = 0; ri < 2; ri++) {
                    int r = rg + 8 * ri;
                    asrcL[si][r][d] = (ring[sl4][r][d] - mL[sl4][d]) * ivL[sl4][d];
                }
            }
        }
        __syncthreads();
        float vv[2];
#pragma unroll
        for (int ri = 0; ri < 2; ri++) {
            int r = rg + 8 * ri;
            float c = (t == 1) ? cur[ri] : 0.f;
#pragma unroll
            for (int ei = 0; ei < 4; ei++) {
                if (ei < nE) {
                    float g = asrcL[ei][r][d] * wgr[ei];
                    g += __shfl_xor(g, 1); g += __shfl_xor(g, 2); g += __shfl_xor(g, 4);
                    g += __shfl_xor(g, 8); g += __shfl_xor(g, 16);
                    g = fminf(fmaxf(g, 0.f), 1.f);
                    tg[ri] += g;
                    float dat = bdr[ei];
                    const float* ar = asrcL[ei][r];
                    const float* wc = &WdL[buf][ei][d];
#pragma unroll
                    for (int k = 0; k < 32; k += 4) {
                        float4 a4 = *(const float4*)&ar[k];
                        dat += a4.x * wc[k * 32] + a4.y * wc[(k + 1) * 32]
                             + a4.z * wc[(k + 2) * 32] + a4.w * wc[(k + 3) * 32];
                    }
                    c += g * dat;
                }
            }
            vv[ri] = fmaxf(c, 0.f);
        }
        __syncthreads();   // all asrcL/ring reads done before ring slot reuse
#pragma unroll
        for (int ri = 0; ri < 2; ri++) {
            int r = rg + 8 * ri;
            ring[t & 3][r][d] = vv[ri];
            if (t >= 14) acts[((size_t)t * BATCH + row0 + r) * DD + d] = vv[ri];
        }
        red[rg][d] = vv[0] + vv[1];
        red[rg][32 + d] = vv[0] * vv[0] + vv[1] * vv[1];
        __syncthreads();
        if (tid < 64) {
            float a = 0.f;
#pragma unroll
            for (int g8 = 0; g8 < 8; g8++) a += red[g8][tid];
            atomicAdd(&stats[((size_t)t * 16 + slot) * 64 + tid], a);
        }
        if (t < 15) {
            __syncthreads();           // vmcnt(0): stats atomics complete at coherent point
            if (tid == 0) atomicAdd(&flag[t], 1);
        }
    }
    if (d == 0) {
        ws[O_TG + row0 + rg] = tg[0];
        ws[O_TG + row0 + rg + 8] = tg[1];
    }
}

// ---- K7: output GEMM [8192x64]@[64x1000] -> f32 out; copy total_gate ----
__global__ void __launch_bounds__(256) k_out(const float* __restrict__ ws, const float* __restrict__ Wout,
                                             float* __restrict__ out) {
    __shared__ float aLt[32][68];    // [d][row], pad to 68
    __shared__ float wL[32][128];    // [k][col]
    __shared__ float mIv[2][2][32];  // [bank][m|iv][d]
    int tid = threadIdx.x;
    int row0 = blockIdx.x * 64;
    int col0 = blockIdx.y * 128;
    const float* acts = ws + O_ACTS;
    if (blockIdx.y == 0 && tid < 64) out[TGOFF + row0 + tid] = ws[O_TG + row0 + tid];
    if (tid < 64) {
        int bi = tid >> 5, d = tid & 31;
        const float* st = ws + O_STATS2 + (size_t)(14 + bi) * 16 * 64;
        float sm = 0.f, sq = 0.f;
#pragma unroll
        for (int sl = 0; sl < 16; sl++) { sm += st[sl * 64 + d]; sq += st[sl * 64 + 32 + d]; }
        float m = sm * (1.f / BATCH);
        float var = sq * (1.f / BATCH) - m * m;
        mIv[bi][0][d] = m;
        mIv[bi][1][d] = rsqrtf(fmaxf(var, 0.f) + BNEPS);
    }
    int tx = tid & 31, ty = tid >> 5;
    int c4 = col0 + tx * 4;
    bool c4ok = (c4 + 3 < NOUT);
    float acc[8][4] = {};
    for (int bi = 0; bi < 2; bi++) {
        __syncthreads();
        {
            int d = tid & 31, r0 = tid >> 5;
            float m = mIv[bi][0][d], iv = mIv[bi][1][d];
            const float* ap = acts + ((size_t)(14 + bi) * BATCH + row0) * DD + d;
#pragma unroll
            for (int i = 0; i < 8; i++) {
                int r = r0 + 8 * i;
                aLt[d][r] = (ap[(size_t)r * DD] - m) * iv;
            }
        }
        {
            const float* wp = Wout + (size_t)bi * DD * NOUT + c4;
            int kk0 = tid >> 5;
#pragma unroll
            for (int i = 0; i < 4; i++) {
                int kk = kk0 + 8 * i;
                const float* wr = wp + (size_t)kk * NOUT;
                float4 v;
                if (c4ok) {
                    v = *(const float4*)wr;
                } else {
                    v.x = (c4 + 0 < NOUT) ? wr[0] : 0.f;
                    v.y = (c4 + 1 < NOUT) ? wr[1] : 0.f;
                    v.z = (c4 + 2 < NOUT) ? wr[2] : 0.f;
                    v.w = (c4 + 3 < NOUT) ? wr[3] : 0.f;
                }
                *(float4*)&wL[kk][tx * 4] = v;
            }
        }
        __syncthreads();
#pragma unroll 4
        for (int k = 0; k < 32; k++) {
            float4 w = *(float4*)&wL[k][tx * 4];
            float4 a0 = *(float4*)&aLt[k][ty * 8];
            float4 a1 = *(float4*)&aLt[k][ty * 8 + 4];
            float ar[8] = {a0.x, a0.y, a0.z, a0.w, a1.x, a1.y, a1.z, a1.w};
            float wc[4] = {w.x, w.y, w.z, w.w};
#pragma unroll
            for (int r = 0; r < 8; r++)
#pragma unroll
                for (int c = 0; c < 4; c++)
                    acc[r][c] += ar[r] * wc[c];
        }
    }
    if (c4ok) {
#pragma unroll
        for (int r = 0; r < 8; r++) {
            int row = row0 + ty * 8 + r;
            *(float4*)&out[(size_t)row * NOUT + c4] =
                make_float4(acc[r][0], acc[r][1], acc[r][2], acc[r][3]);
        }
    } else {
#pragma unroll
        for (int r = 0; r < 8; r++) {
            int row = row0 + ty * 8 + r;
#pragma unroll
            for (int c = 0; c < 4; c++)
                if (c4 + c < NOUT) out[(size_t)row * NOUT + c4 + c] = acc[r][c];
        }
    }
}

extern "C" void kernel_launch(void* const* d_in, const int* in_sizes, int n_in,
                              void* d_out, int out_size, void* d_ws, size_t ws_size,
                              hipStream_t stream) {
    (void)in_sizes; (void)n_in; (void)out_size; (void)ws_size;
    const float* x     = (const float*)d_in[0];
    const float* gamma = (const float*)d_in[1];
    const float* beta  = (const float*)d_in[2];
    const float* W_in  = (const float*)d_in[3];
    const float* b_in  = (const float*)d_in[4];
    const float* Wg    = (const float*)d_in[5];
    const float* Wd    = (const float*)d_in[6];
    const float* bd    = (const float*)d_in[7];
    const float* Wout  = (const float*)d_in[8];
    float* out = (float*)d_out;
    float* ws  = (float*)d_ws;

    hipMemsetAsync(d_ws, 0, ZERO_FLOATS * sizeof(float), stream);
    k_stats<<<dim3(12, 64), 256, 0, stream>>>(x, ws);
    k_prep<<<12, 256, 0, stream>>>(ws, gamma, beta, b_in);
    k_bias<<<24, 256, 0, stream>>>(ws, W_in);
    k_bfold<<<768, 256, 0, stream>>>(ws, W_in);
    k_gemm3<<<dim3(128, 4), 256, 0, stream>>>(x, ws);
    k_act<<<512, 256, 0, stream>>>(ws);
    // re-zero barrier flags (O_SUM region is dead after k_prep; stream-ordered)
    hipMemsetAsync(ws + O_FLAG, 0, 16 * sizeof(int), stream);
    k_banks<<<NBLK, 256, 0, stream>>>(ws, Wg, Wd, bd);
    k_out<<<dim3(128, 8), 256, 0, stream>>>(ws, Wout, out);
}

// Round 5
// 375.819 us; speedup vs baseline: 1.1600x; 1.1521x over previous
//
#include <hip/hip_runtime.h>

// RouteNet f32. stats -> prep -> bias/bfold -> k_gemm3 -> k_act(+bank0 stats)
// -> k_banks (fused, 15 stages, atomic-flag barriers) -> k_out.
// R7: k_out 64x128 tile (123->~20us). R8/9: gemm3 dbuf regressed -> reverted.
// R10: fused k_banks, 512blk x 16rows: 178us profiled (~12us/stage) - barrier path
//   too fat: 1024 scalar atomic stats loads/block/stage, 4-bank renormalize, all
//   compute inside the post-barrier segment.
// R11 (this): barrier critical path diet:
//   - 4 stats slots (was 16); stats re-read = 1 load/thread (256 vs 1024/block)
//   - ring holds NORMALIZED acts; each bank normalized once (in place) at stage s+1
//   - edges from banks <= t-2 computed BEFORE the flag wait (only the t-1 edge after)
//   - 256 blocks x 32 rows: halves barrier participants/contention/skew

#define BATCH 8192
#define NIN 3072
#define DD 32
#define NB 16
#define NOUT 1000
#define TGOFF (BATCH * NOUT)
#define BNEPS 1e-5f
#define NBLK 256
#define ROWS 32

// ws float offsets
#define O_SUM 0          // [3072] (dead after k_prep; first 16 reused as barrier flags)
#define O_FLAG 0         // [16] int flags, re-zeroed by memset after k_prep
#define O_SUM2 3072      // [3072]
#define O_STATS2 6144    // [16 banks][4 slots][64] sum/sumsq
#define O_TG 22528       // [8192]
#define ZERO_FLOATS 30720
#define O_SCALE 30720    // [3072]
#define O_SHIFT 33792    // [3072]
#define O_BIAS 36864     // [64]
#define O_BP 36928       // [3072][64] folded B'
#define O_ACTS 233536    // [16][8192][32] raw acts (banks 0,1,14,15 used)
#define O_ACC (O_ACTS + 2 * BATCH * DD)   // [4][8192][64] gemm partials

// ---- K1: column stats of x ----
__global__ void __launch_bounds__(256) k_stats(const float* __restrict__ x, float* __restrict__ ws) {
    int c = blockIdx.x * 256 + threadIdx.x;
    const float* p = x + (size_t)blockIdx.y * 128 * NIN + c;
    float s = 0.f, s2 = 0.f;
#pragma unroll 8
    for (int i = 0; i < 128; i++) { float v = p[(size_t)i * NIN]; s += v; s2 += v * v; }
    atomicAdd(&ws[O_SUM + c], s);
    atomicAdd(&ws[O_SUM2 + c], s2);
}

// ---- K2: scale/shift; seed fused bias with b_in ----
__global__ void __launch_bounds__(256) k_prep(float* __restrict__ ws, const float* __restrict__ g,
                                              const float* __restrict__ b, const float* __restrict__ b_in) {
    int c = blockIdx.x * 256 + threadIdx.x;
    float mean = ws[O_SUM + c] * (1.f / BATCH);
    float var = ws[O_SUM2 + c] * (1.f / BATCH) - mean * mean;
    float sc = g[c] * rsqrtf(fmaxf(var, 0.f) + BNEPS);
    ws[O_SCALE + c] = sc;
    ws[O_SHIFT + c] = b[c] - mean * sc;
    if (c < 64) ws[O_BIAS + c] = b_in[c];
}

// ---- K3a: bias' += shift @ W_in ----
__global__ void __launch_bounds__(256) k_bias(float* __restrict__ ws, const float* __restrict__ W_in) {
    int bank = blockIdx.x & 1, jc = blockIdx.x >> 1;
    int d = threadIdx.x & 31, js = threadIdx.x >> 5;
    int j0 = jc * 256 + js * 32;
    float a = 0.f;
    for (int j = 0; j < 32; j++)
        a += ws[O_SHIFT + j0 + j] * W_in[(size_t)bank * NIN * DD + (size_t)(j0 + j) * DD + d];
    __shared__ float red[8][32];
    red[js][d] = a;
    __syncthreads();
    if (threadIdx.x < 32) {
        float t = 0.f;
#pragma unroll
        for (int g8 = 0; g8 < 8; g8++) t += red[g8][threadIdx.x];
        atomicAdd(&ws[O_BIAS + bank * 32 + threadIdx.x], t);
    }
}

// ---- K3b: B'[j][c] = scale[j] * W_in[c>>5][j][c&31] ----
__global__ void __launch_bounds__(256) k_bfold(float* __restrict__ ws, const float* __restrict__ W_in) {
    int idx = blockIdx.x * 256 + threadIdx.x;
    int j = idx >> 6, c = idx & 63;
    ws[O_BP + idx] = ws[O_SCALE + j] * W_in[(size_t)(c >> 5) * NIN * DD + (size_t)j * DD + (c & 31)];
}

// ---- K4: input GEMM. grid (128,4). R0 proven version (71.6us, VGPR 56). ----
__global__ void __launch_bounds__(256) k_gemm3(const float* __restrict__ x, float* __restrict__ ws) {
    __shared__ float xL[64][20];
    __shared__ float bL[16][64];
    int tid = threadIdx.x;
    int row0 = blockIdx.x * 64;
    int k00 = blockIdx.y * 768;
    const float* bp = ws + O_BP;
    float acc[4][4] = {};
    int tx = tid & 15, rt = tid >> 4;
    int lr = tid >> 2, lq = tid & 3;
    int br = tid >> 4, bq = tid & 15;
    for (int kc = 0; kc < 48; kc++) {
        int k0 = k00 + kc * 16;
        float4 xv = *(const float4*)&x[(size_t)(row0 + lr) * NIN + k0 + lq * 4];
        float4 bv = *(const float4*)&bp[(size_t)(k0 + br) * 64 + bq * 4];
        __syncthreads();
        *(float4*)&xL[lr][lq * 4] = xv;
        *(float4*)&bL[br][bq * 4] = bv;
        __syncthreads();
#pragma unroll
        for (int kk = 0; kk < 16; kk += 4) {
            float4 b0 = *(float4*)&bL[kk][tx * 4];
            float4 b1 = *(float4*)&bL[kk + 1][tx * 4];
            float4 b2 = *(float4*)&bL[kk + 2][tx * 4];
            float4 b3 = *(float4*)&bL[kk + 3][tx * 4];
#pragma unroll
            for (int j = 0; j < 4; j++) {
                float4 xv4 = *(float4*)&xL[rt * 4 + j][kk];
                acc[j][0] += xv4.x * b0.x + xv4.y * b1.x + xv4.z * b2.x + xv4.w * b3.x;
                acc[j][1] += xv4.x * b0.y + xv4.y * b1.y + xv4.z * b2.y + xv4.w * b3.y;
                acc[j][2] += xv4.x * b0.z + xv4.y * b1.z + xv4.z * b2.z + xv4.w * b3.z;
                acc[j][3] += xv4.x * b0.w + xv4.y * b1.w + xv4.z * b2.w + xv4.w * b3.w;
            }
        }
    }
    float* dst = ws + O_ACC + (size_t)blockIdx.y * (BATCH * 64);
#pragma unroll
    for (int j = 0; j < 4; j++) {
        float4 v = make_float4(acc[j][0], acc[j][1], acc[j][2], acc[j][3]);
        *(float4*)&dst[(size_t)(row0 + rt * 4 + j) * 64 + tx * 4] = v;
    }
}

// ---- K5: reduce partials + bias + relu -> acts banks 0/1; bank-0 stats (4 slots) ----
__global__ void __launch_bounds__(256) k_act(float* __restrict__ ws) {
    __shared__ float sred[16][32];
    __shared__ float qred[16][32];
    int tid = threadIdx.x;
    int i4 = (blockIdx.x * 256 + tid) * 4;
    const float* ac = ws + O_ACC;
    float4 s0 = *(const float4*)&ac[i4];
    float4 s1 = *(const float4*)&ac[524288 + i4];
    float4 s2 = *(const float4*)&ac[1048576 + i4];
    float4 s3 = *(const float4*)&ac[1572864 + i4];
    int c = i4 & 63, row = i4 >> 6;
    const float* bias = ws + O_BIAS;
    float4 v;
    v.x = fmaxf(s0.x + s1.x + s2.x + s3.x + bias[c], 0.f);
    v.y = fmaxf(s0.y + s1.y + s2.y + s3.y + bias[c + 1], 0.f);
    v.z = fmaxf(s0.z + s1.z + s2.z + s3.z + bias[c + 2], 0.f);
    v.w = fmaxf(s0.w + s1.w + s2.w + s3.w + bias[c + 3], 0.f);
    int bank = c >> 5, dd = c & 31;
    *(float4*)&ws[O_ACTS + ((size_t)bank * BATCH + row) * DD + dd] = v;
    int r16 = tid >> 4;
    if (bank == 0) {
        *(float4*)&sred[r16][dd] = v;
        *(float4*)&qred[r16][dd] = make_float4(v.x * v.x, v.y * v.y, v.z * v.z, v.w * v.w);
    }
    __syncthreads();
    if (tid < 32) {
        float sm = 0.f, sq = 0.f;
#pragma unroll
        for (int r = 0; r < 16; r++) { sm += sred[r][tid]; sq += qred[r][tid]; }
        int slot = blockIdx.x & 3;
        float* st = ws + O_STATS2 + (size_t)slot * 64;   // bank 0
        atomicAdd(&st[tid], sm);
        atomicAdd(&st[32 + tid], sq);
    }
}

// ---- K6: banks t=1..15 fused. 256 blocks x 32 rows (1/CU). Ring holds NORMALIZED
// acts (each bank normalized in place once). Early edges computed before flag wait.
__global__ void __launch_bounds__(256, 2) k_banks(float* __restrict__ ws,
                                                  const float* __restrict__ Wg,
                                                  const float* __restrict__ Wd,
                                                  const float* __restrict__ bd) {
    __shared__ float ring[4][ROWS][32];    // normalized acts, bank s in slot s&3
    __shared__ float WdL[2][4][1024];      // double-buffered edge weights
    __shared__ float sred4[4][64];
    __shared__ float m_s[32], iv_s[32];
    __shared__ float red[8][64];
    int tid = threadIdx.x;
    int rg = tid >> 5, d = tid & 31;
    int row0 = blockIdx.x * ROWS;
    int slot4 = blockIdx.x & 3;
    float* acts = ws + O_ACTS;
    float* stats = ws + O_STATS2;
    int* flag = (int*)(ws + O_FLAG);
    float tg[4] = {0.f, 0.f, 0.f, 0.f};
    float cur[4];
    // prologue: raw bank0 -> ring slot0; bank1 partial -> cur; bank0 stats -> m/iv
#pragma unroll
    for (int ri = 0; ri < 4; ri++) {
        int r = rg + 8 * ri;
        ring[0][r][d] = acts[(size_t)(row0 + r) * DD + d];
        cur[ri] = acts[((size_t)BATCH + row0 + r) * DD + d];
    }
    sred4[tid >> 6][tid & 63] = stats[(size_t)(tid >> 6) * 64 + (tid & 63)];  // kernel boundary: plain ok
    __syncthreads();
    if (tid < 32) {
        float sm = sred4[0][tid] + sred4[1][tid] + sred4[2][tid] + sred4[3][tid];
        float sq = sred4[0][32 + tid] + sred4[1][32 + tid] + sred4[2][32 + tid] + sred4[3][32 + tid];
        float m = sm * (1.f / BATCH);
        float var = sq * (1.f / BATCH) - m * m;
        m_s[tid] = m;
        iv_s[tid] = rsqrtf(fmaxf(var, 0.f) + BNEPS);
    }
    // prefetch stage-1 Wd (1 edge) into WdL[1]
    ((float4*)&WdL[1][0][0])[tid] = ((const float4*)Wd)[tid];
    __syncthreads();
#pragma unroll
    for (int ri = 0; ri < 4; ri++) {   // normalize bank0 in place
        int r = rg + 8 * ri;
        ring[0][r][d] = (ring[0][r][d] - m_s[d]) * iv_s[d];
    }
    __syncthreads();
    for (int t = 1; t < 16; t++) {
        int buf = t & 1;
        int nE = t < 4 ? t : 4;
        int s0 = t - nE;
        int eb = (t <= 4) ? t * (t - 1) / 2 : 10 + 4 * (t - 5);
        // prefetch next stage's Wd into other buffer
        if (t < 15) {
            int t2 = t + 1;
            int nE2 = t2 < 4 ? t2 : 4;
            int eb2 = (t2 <= 4) ? t2 * (t2 - 1) / 2 : 10 + 4 * (t2 - 5);
            for (int p = tid; p < nE2 * 256; p += 256)
                ((float4*)&WdL[buf ^ 1][0][0])[p] = ((const float4*)(Wd + (size_t)eb2 * 1024))[p];
        }
        float wgr[4], bdr[4];
#pragma unroll
        for (int ei = 0; ei < 4; ei++) {
            wgr[ei] = (ei < nE) ? Wg[(eb + ei) * 32 + d] : 0.f;
            bdr[ei] = (ei < nE) ? bd[(eb + ei) * 32 + d] : 0.f;
        }
        float c_[4];
#pragma unroll
        for (int ri = 0; ri < 4; ri++) c_[ri] = (t == 1) ? cur[ri] : 0.f;
        // EARLY edges (sources <= t-2, already normalized in ring)
#pragma unroll
        for (int ei = 0; ei < 3; ei++) {
            if (ei < nE - 1) {
                int sl = (s0 + ei) & 3;
#pragma unroll
                for (int ri = 0; ri < 4; ri++) {
                    int r = rg + 8 * ri;
                    float g = ring[sl][r][d] * wgr[ei];
                    g += __shfl_xor(g, 1); g += __shfl_xor(g, 2); g += __shfl_xor(g, 4);
                    g += __shfl_xor(g, 8); g += __shfl_xor(g, 16);
                    g = fminf(fmaxf(g, 0.f), 1.f);
                    tg[ri] += g;
                    float dat = bdr[ei];
                    const float* ar = ring[sl][r];
                    const float* wc = &WdL[buf][ei][d];
#pragma unroll
                    for (int k = 0; k < 32; k += 4) {
                        float4 a4 = *(const float4*)&ar[k];
                        dat += a4.x * wc[k * 32] + a4.y * wc[(k + 1) * 32]
                             + a4.z * wc[(k + 2) * 32] + a4.w * wc[(k + 3) * 32];
                    }
                    c_[ri] += g * dat;
                }
            }
        }
        // barrier: wait bank t-1 stats; read (1 load/thread); normalize slot (t-1)&3
        if (t > 1) {
            if (tid == 0) {
                while (__hip_atomic_load(&flag[t - 1], __ATOMIC_RELAXED, __HIP_MEMORY_SCOPE_AGENT) < NBLK)
                    __builtin_amdgcn_s_sleep(8);
            }
            __syncthreads();
            sred4[tid >> 6][tid & 63] = __hip_atomic_load(
                &stats[((size_t)(t - 1) * 4 + (tid >> 6)) * 64 + (tid & 63)],
                __ATOMIC_RELAXED, __HIP_MEMORY_SCOPE_AGENT);
            __syncthreads();
            if (tid < 32) {
                float sm = sred4[0][tid] + sred4[1][tid] + sred4[2][tid] + sred4[3][tid];
                float sq = sred4[0][32 + tid] + sred4[1][32 + tid] + sred4[2][32 + tid] + sred4[3][32 + tid];
                float m = sm * (1.f / BATCH);
                float var = sq * (1.f / BATCH) - m * m;
                m_s[tid] = m;
                iv_s[tid] = rsqrtf(fmaxf(var, 0.f) + BNEPS);
            }
            __syncthreads();
            int sl = (t - 1) & 3;
#pragma unroll
            for (int ri = 0; ri < 4; ri++) {
                int r = rg + 8 * ri;
                ring[sl][r][d] = (ring[sl][r][d] - m_s[d]) * iv_s[d];
            }
            __syncthreads();
        }
        // LATE edge (source t-1)
        {
            int ei = nE - 1;
            int sl = (t - 1) & 3;
#pragma unroll
            for (int ri = 0; ri < 4; ri++) {
                int r = rg + 8 * ri;
                float g = ring[sl][r][d] * wgr[ei];
                g += __shfl_xor(g, 1); g += __shfl_xor(g, 2); g += __shfl_xor(g, 4);
                g += __shfl_xor(g, 8); g += __shfl_xor(g, 16);
                g = fminf(fmaxf(g, 0.f), 1.f);
                tg[ri] += g;
                float dat = bdr[ei];
                const float* ar = ring[sl][r];
                const float* wc = &WdL[buf][ei][d];
#pragma unroll
                for (int k = 0; k < 32; k += 4) {
                    float4 a4 = *(const float4*)&ar[k];
                    dat += a4.x * wc[k * 32] + a4.y * wc[(k + 1) * 32]
                         + a4.z * wc[(k + 2) * 32] + a4.w * wc[(k + 3) * 32];
                }
                c_[ri] += g * dat;
            }
        }
        float vv[4];
#pragma unroll
        for (int ri = 0; ri < 4; ri++) vv[ri] = fmaxf(c_[ri], 0.f);
        __syncthreads();   // all ring reads done before slot t&3 overwrite
#pragma unroll
        for (int ri = 0; ri < 4; ri++) {
            int r = rg + 8 * ri;
            ring[t & 3][r][d] = vv[ri];   // raw; normalized at stage t+1
            if (t >= 14) acts[((size_t)t * BATCH + row0 + r) * DD + d] = vv[ri];
        }
        red[rg][d] = vv[0] + vv[1] + vv[2] + vv[3];
        red[rg][32 + d] = vv[0] * vv[0] + vv[1] * vv[1] + vv[2] * vv[2] + vv[3] * vv[3];
        __syncthreads();
        if (tid < 64) {
            float a = 0.f;
#pragma unroll
            for (int g8 = 0; g8 < 8; g8++) a += red[g8][tid];
            atomicAdd(&stats[((size_t)t * 4 + slot4) * 64 + tid], a);
        }
        if (t < 15) {
            __syncthreads();           // drains vmcnt: stats atomics at coherent point
            if (tid == 0) atomicAdd(&flag[t], 1);
        }
    }
    if (d == 0) {
#pragma unroll
        for (int ri = 0; ri < 4; ri++) ws[O_TG + row0 + rg + 8 * ri] = tg[ri];
    }
}

// ---- K7: output GEMM; copy total_gate. 64x128 tile, grid (128,8). ----
__global__ void __launch_bounds__(256) k_out(const float* __restrict__ ws, const float* __restrict__ Wout,
                                             float* __restrict__ out) {
    __shared__ float aLt[32][68];
    __shared__ float wL[32][128];
    __shared__ float mIv[2][2][32];
    int tid = threadIdx.x;
    int row0 = blockIdx.x * 64;
    int col0 = blockIdx.y * 128;
    const float* acts = ws + O_ACTS;
    if (blockIdx.y == 0 && tid < 64) out[TGOFF + row0 + tid] = ws[O_TG + row0 + tid];
    if (tid < 64) {
        int bi = tid >> 5, d = tid & 31;
        const float* st = ws + O_STATS2 + (size_t)(14 + bi) * 4 * 64;
        float sm = 0.f, sq = 0.f;
#pragma unroll
        for (int sl = 0; sl < 4; sl++) { sm += st[sl * 64 + d]; sq += st[sl * 64 + 32 + d]; }
        float m = sm * (1.f / BATCH);
        float var = sq * (1.f / BATCH) - m * m;
        mIv[bi][0][d] = m;
        mIv[bi][1][d] = rsqrtf(fmaxf(var, 0.f) + BNEPS);
    }
    int tx = tid & 31, ty = tid >> 5;
    int c4 = col0 + tx * 4;
    bool c4ok = (c4 + 3 < NOUT);
    float acc[8][4] = {};
    for (int bi = 0; bi < 2; bi++) {
        __syncthreads();
        {
            int d = tid & 31, r0 = tid >> 5;
            float m = mIv[bi][0][d], iv = mIv[bi][1][d];
            const float* ap = acts + ((size_t)(14 + bi) * BATCH + row0) * DD + d;
#pragma unroll
            for (int i = 0; i < 8; i++) {
                int r = r0 + 8 * i;
                aLt[d][r] = (ap[(size_t)r * DD] - m) * iv;
            }
        }
        {
            const float* wp = Wout + (size_t)bi * DD * NOUT + c4;
            int kk0 = tid >> 5;
#pragma unroll
            for (int i = 0; i < 4; i++) {
                int kk = kk0 + 8 * i;
                const float* wr = wp + (size_t)kk * NOUT;
                float4 v;
                if (c4ok) {
                    v = *(const float4*)wr;
                } else {
                    v.x = (c4 + 0 < NOUT) ? wr[0] : 0.f;
                    v.y = (c4 + 1 < NOUT) ? wr[1] : 0.f;
                    v.z = (c4 + 2 < NOUT) ? wr[2] : 0.f;
                    v.w = (c4 + 3 < NOUT) ? wr[3] : 0.f;
                }
                *(float4*)&wL[kk][tx * 4] = v;
            }
        }
        __syncthreads();
#pragma unroll 4
        for (int k = 0; k < 32; k++) {
            float4 w = *(float4*)&wL[k][tx * 4];
            float4 a0 = *(float4*)&aLt[k][ty * 8];
            float4 a1 = *(float4*)&aLt[k][ty * 8 + 4];
            float ar[8] = {a0.x, a0.y, a0.z, a0.w, a1.x, a1.y, a1.z, a1.w};
            float wc[4] = {w.x, w.y, w.z, w.w};
#pragma unroll
            for (int r = 0; r < 8; r++)
#pragma unroll
                for (int c = 0; c < 4; c++)
                    acc[r][c] += ar[r] * wc[c];
        }
    }
    if (c4ok) {
#pragma unroll
        for (int r = 0; r < 8; r++) {
            int row = row0 + ty * 8 + r;
            *(float4*)&out[(size_t)row * NOUT + c4] =
                make_float4(acc[r][0], acc[r][1], acc[r][2], acc[r][3]);
        }
    } else {
#pragma unroll
        for (int r = 0; r < 8; r++) {
            int row = row0 + ty * 8 + r;
#pragma unroll
            for (int c = 0; c < 4; c++)
                if (c4 + c < NOUT) out[(size_t)row * NOUT + c4 + c] = acc[r][c];
        }
    }
}

extern "C" void kernel_launch(void* const* d_in, const int* in_sizes, int n_in,
                              void* d_out, int out_size, void* d_ws, size_t ws_size,
                              hipStream_t stream) {
    (void)in_sizes; (void)n_in; (void)out_size; (void)ws_size;
    const float* x     = (const float*)d_in[0];
    const float* gamma = (const float*)d_in[1];
    const float* beta  = (const float*)d_in[2];
    const float* W_in  = (const float*)d_in[3];
    const float* b_in  = (const float*)d_in[4];
    const float* Wg    = (const float*)d_in[5];
    const float* Wd    = (const float*)d_in[6];
    const float* bd    = (const float*)d_in[7];
    const float* Wout  = (const float*)d_in[8];
    float* out = (float*)d_out;
    float* ws  = (float*)d_ws;

    hipMemsetAsync(d_ws, 0, ZERO_FLOATS * sizeof(float), stream);
    k_stats<<<dim3(12, 64), 256, 0, stream>>>(x, ws);
    k_prep<<<12, 256, 0, stream>>>(ws, gamma, beta, b_in);
    k_bias<<<24, 256, 0, stream>>>(ws, W_in);
    k_bfold<<<768, 256, 0, stream>>>(ws, W_in);
    k_gemm3<<<dim3(128, 4), 256, 0, stream>>>(x, ws);
    k_act<<<512, 256, 0, stream>>>(ws);
    // re-zero barrier flags (O_SUM region dead after k_prep; stream-ordered)
    hipMemsetAsync(ws + O_FLAG, 0, 16 * sizeof(int), stream);
    k_banks<<<NBLK, 256, 0, stream>>>(ws, Wg, Wd, bd);
    k_out<<<dim3(128, 8), 256, 0, stream>>>(ws, Wout, out);
}